// Round 3
// baseline (172.344 us; speedup 1.0000x reference)
//
#include <hip/hip_runtime.h>
#include <stdint.h>

#define N_PTS 65536
#define NB1 32768        // level-1 bins: score bits 31:16
#define NB2 4096         // level-2 bins: score bits 15:4 within bin B*
#define CAND_CAP 4096
#define FCAP 1024
#define PK_FLOATS 4096   // 16KB packed uniform weight blob (all 5 layers)
typedef unsigned long long u64;

// ws layout (zero region [256K, 256K+144K+64) contiguous)
//   [0    , 256K)        scores  f32[65536]
//   [256K , 384K)        hist1   u32[32768]
//   [384K , 400K)        hist2   u32[4096]
//   [400K , 400K+64)     meta    i32 {0:Bstar, 1:tail1, 2:cand_count}
//   [408K , 440K)        cand    u64[4096]   (not zeroed; meta[2] counts)
//   [440K , 456K)        pk      f32[4096]   packed uniform weight blob

// ---------------------------------------------------------------------------
// K0: zero hist1/hist2/meta AND (last block) pack the weight blob.
// pk float layout:
//   [0,256):       layer1  [j][0:6]=W1 row j, [6]=b1[j], [7]=0
//   [256+jb*112):  per neuron-pair jb: W2 row 2jb (32), W2 row 2jb+1 (32),
//                  Wa col 2jb (16), Wa col 2jb+1 (16), b2[2jb], b2[2jb+1], pad
//   [3840,3856):   ba      [3856,3984): Wb    [3984,3992): bb
//   [3992,4000):   Wc      [4000]: bc         rest 0
// ---------------------------------------------------------------------------
__global__ __launch_bounds__(256) void zero_pack_kernel(
    uint4* __restrict__ z, int n4,
    const float* __restrict__ W1, const float* __restrict__ b1,
    const float* __restrict__ W2, const float* __restrict__ b2,
    const float* __restrict__ Wa, const float* __restrict__ ba,
    const float* __restrict__ Wb, const float* __restrict__ bb,
    const float* __restrict__ Wc, const float* __restrict__ bc,
    float* __restrict__ pk)
{
    const int t = threadIdx.x;
    const int i = blockIdx.x * 256 + t;
    const uint4 zz = {0u, 0u, 0u, 0u};
    if (i < n4) z[i] = zz;

    if (blockIdx.x == gridDim.x - 1) {
        for (int e = t; e < PK_FLOATS; e += 256) {
            float v;
            if (e < 256) {
                const int j = e >> 3, c = e & 7;
                v = (c < 6) ? W1[j * 6 + c] : ((c == 6) ? b1[j] : 0.f);
            } else if (e < 3840) {
                const int r = e - 256;
                const int jb = r / 112, k = r % 112;
                if (k < 32)       v = W2[(2 * jb) * 32 + k];
                else if (k < 64)  v = W2[(2 * jb + 1) * 32 + (k - 32)];
                else if (k < 80)  v = Wa[(k - 64) * 64 + 2 * jb];
                else if (k < 96)  v = Wa[(k - 80) * 64 + (2 * jb + 1)];
                else if (k == 96) v = b2[2 * jb];
                else if (k == 97) v = b2[2 * jb + 1];
                else              v = 0.f;
            }
            else if (e < 3856) v = ba[e - 3840];
            else if (e < 3984) v = Wb[e - 3856];
            else if (e < 3992) v = bb[e - 3984];
            else if (e < 4000) v = Wc[e - 3992];
            else if (e == 4000) v = bc[0];
            else v = 0.f;
            pk[e] = v;
        }
    }
}

// batched uniform loads: issue N asm-volatile loads (forced distinct output
// regs, ordered), then ONE vmcnt(0) drain + sched_barrier(0) (rule-18 fence:
// without it the consumer FMAs hoist past the wait).
#define GL4(dst, imm) asm volatile("global_load_dwordx4 %0, %1, %2 offset:" #imm \
    : "=v"(dst) : "v"(voff), "s"(pkp))
#define GL2(dst, imm) asm volatile("global_load_dwordx2 %0, %1, %2 offset:" #imm \
    : "=v"(dst) : "v"(voff), "s"(pkp))
#define GL1(dst, imm) asm volatile("global_load_dword %0, %1, %2 offset:" #imm \
    : "=v"(dst) : "v"(voff), "s"(pkp))
#define WAITV0() do { asm volatile("s_waitcnt vmcnt(0)" ::: "memory"); \
    __builtin_amdgcn_sched_barrier(0); } while (0)

// ---------------------------------------------------------------------------
// K1: MLP score (batch 0). 256 blocks x 256 threads, one point per thread
// (65536 threads = 1024 waves = 1 wave/SIMD chip-wide: TLP is maxed; the
// only lever is killing serial latency exposures). R1/R2 both measured
// ~57us with VALUBusy <14%: the compiler dribbled the 24 weight loads one
// latency at a time (VGPR=88 proves no batch was ever live). Here every
// uniform weight fetch is an explicitly batched asm global_load from the
// L2/L3-resident 16KB blob: one latency exposure per jb iteration (32
// total) instead of ~26 per iteration.
// LDS holds ONLY the 64KB packed-u16 level-1 histogram.
// ---------------------------------------------------------------------------
__global__ __launch_bounds__(256, 1) void score_kernel(
    const float* __restrict__ src, const float* __restrict__ pk,
    float* __restrict__ scores, unsigned* __restrict__ hist1)
{
    __shared__ unsigned histL[NB1 / 2];            // 64 KB, u16 pairs
    const int t = threadIdx.x;
    const float* pkp = pk;

    // zero LDS hist: 4096 uint4 / 256 thr = 16 per thread
    {
        uint4* h4 = (uint4*)histL;
        const uint4 zz = {0u, 0u, 0u, 0u};
        #pragma unroll
        for (int i = 0; i < 16; i++) h4[t + 256 * i] = zz;
    }
    __syncthreads();

    const int p = blockIdx.x * 256 + t;

    float x[6];
    #pragma unroll
    for (int c = 0; c < 6; c++) x[c] = src[c * N_PTS + p];

    // ---- layer 1: 6 -> 32, four 16-load batches ----
    float h1[32];
    #pragma unroll
    for (int g = 0; g < 4; g++) {
        const unsigned voff = (unsigned)(g * 256);
        float4 w[16];
        GL4(w[0],  0);   GL4(w[1],  16);  GL4(w[2],  32);  GL4(w[3],  48);
        GL4(w[4],  64);  GL4(w[5],  80);  GL4(w[6],  96);  GL4(w[7],  112);
        GL4(w[8],  128); GL4(w[9],  144); GL4(w[10], 160); GL4(w[11], 176);
        GL4(w[12], 192); GL4(w[13], 208); GL4(w[14], 224); GL4(w[15], 240);
        WAITV0();
        #pragma unroll
        for (int jj = 0; jj < 8; jj++) {
            const float4 wA = w[2 * jj];
            const float4 wB = w[2 * jj + 1];       // .z = bias
            float a = wB.z;
            a = fmaf(wA.x, x[0], a); a = fmaf(wA.y, x[1], a);
            a = fmaf(wA.z, x[2], a); a = fmaf(wA.w, x[3], a);
            a = fmaf(wB.x, x[4], a); a = fmaf(wB.y, x[5], a);
            h1[8 * g + jj] = fmaxf(a, 0.f);
        }
    }

    // ---- ba batch -> h3 init ----
    float h3[16];
    {
        const unsigned voff = 15360u;
        float4 ba4[4];
        GL4(ba4[0], 0); GL4(ba4[1], 16); GL4(ba4[2], 32); GL4(ba4[3], 48);
        WAITV0();
        #pragma unroll
        for (int q4 = 0; q4 < 4; q4++) {
            h3[4 * q4 + 0] = ba4[q4].x; h3[4 * q4 + 1] = ba4[q4].y;
            h3[4 * q4 + 2] = ba4[q4].z; h3[4 * q4 + 3] = ba4[q4].w;
        }
    }

    // ---- layers 2+3 fused: 32 -> 64 -> 16, neuron pairs ----
    #pragma unroll 1
    for (int jb = 0; jb < 32; jb++) {
        const unsigned voff = 1024u + (unsigned)jb * 448u;
        float4 u[8], v[8], q0[4], q1[4];
        float2 bj2;
        GL4(u[0], 0);    GL4(u[1], 16);   GL4(u[2], 32);   GL4(u[3], 48);
        GL4(u[4], 64);   GL4(u[5], 80);   GL4(u[6], 96);   GL4(u[7], 112);
        GL4(v[0], 128);  GL4(v[1], 144);  GL4(v[2], 160);  GL4(v[3], 176);
        GL4(v[4], 192);  GL4(v[5], 208);  GL4(v[6], 224);  GL4(v[7], 240);
        GL4(q0[0], 256); GL4(q0[1], 272); GL4(q0[2], 288); GL4(q0[3], 304);
        GL4(q1[0], 320); GL4(q1[1], 336); GL4(q1[2], 352); GL4(q1[3], 368);
        GL2(bj2, 384);
        WAITV0();
        const float bj0 = bj2.x, bj1 = bj2.y;

        float a0 = 0.f, a1 = 0.f, a2 = 0.f, a3 = 0.f;  // neuron j0
        float c0 = 0.f, c1 = 0.f, c2 = 0.f, c3 = 0.f;  // neuron j1
        #pragma unroll
        for (int i4 = 0; i4 < 8; i4++) {
            const float h0 = h1[4 * i4 + 0], hh1 = h1[4 * i4 + 1];
            const float h2 = h1[4 * i4 + 2], hh3 = h1[4 * i4 + 3];
            a0 = fmaf(u[i4].x, h0, a0); a1 = fmaf(u[i4].y, hh1, a1);
            a2 = fmaf(u[i4].z, h2, a2); a3 = fmaf(u[i4].w, hh3, a3);
            c0 = fmaf(v[i4].x, h0, c0); c1 = fmaf(v[i4].y, hh1, c1);
            c2 = fmaf(v[i4].z, h2, c2); c3 = fmaf(v[i4].w, hh3, c3);
        }
        const float v0 = fmaxf((a0 + a1) + (a2 + a3) + bj0, 0.f);
        const float v1 = fmaxf((c0 + c1) + (c2 + c3) + bj1, 0.f);
        #pragma unroll
        for (int q4 = 0; q4 < 4; q4++) {
            float t0 = h3[4 * q4 + 0], t1 = h3[4 * q4 + 1];
            float t2 = h3[4 * q4 + 2], t3 = h3[4 * q4 + 3];
            t0 = fmaf(q0[q4].x, v0, t0); t1 = fmaf(q0[q4].y, v0, t1);
            t2 = fmaf(q0[q4].z, v0, t2); t3 = fmaf(q0[q4].w, v0, t3);
            t0 = fmaf(q1[q4].x, v1, t0); t1 = fmaf(q1[q4].y, v1, t1);
            t2 = fmaf(q1[q4].z, v1, t2); t3 = fmaf(q1[q4].w, v1, t3);
            h3[4 * q4 + 0] = t0; h3[4 * q4 + 1] = t1;
            h3[4 * q4 + 2] = t2; h3[4 * q4 + 3] = t3;
        }
    }
    #pragma unroll
    for (int q = 0; q < 16; q++) h3[q] = fmaxf(h3[q], 0.f);

    // ---- layers 4+5: 16 -> 8 -> 1, one 37-load batch ----
    float z;
    {
        const unsigned voff = 15360u;
        float4 wb4[32], bb4[2], wc4[2];
        float bcv;
        GL4(wb4[0],  64);  GL4(wb4[1],  80);  GL4(wb4[2],  96);  GL4(wb4[3],  112);
        GL4(wb4[4],  128); GL4(wb4[5],  144); GL4(wb4[6],  160); GL4(wb4[7],  176);
        GL4(wb4[8],  192); GL4(wb4[9],  208); GL4(wb4[10], 224); GL4(wb4[11], 240);
        GL4(wb4[12], 256); GL4(wb4[13], 272); GL4(wb4[14], 288); GL4(wb4[15], 304);
        GL4(wb4[16], 320); GL4(wb4[17], 336); GL4(wb4[18], 352); GL4(wb4[19], 368);
        GL4(wb4[20], 384); GL4(wb4[21], 400); GL4(wb4[22], 416); GL4(wb4[23], 432);
        GL4(wb4[24], 448); GL4(wb4[25], 464); GL4(wb4[26], 480); GL4(wb4[27], 496);
        GL4(wb4[28], 512); GL4(wb4[29], 528); GL4(wb4[30], 544); GL4(wb4[31], 560);
        GL4(bb4[0], 576);  GL4(bb4[1], 592);
        GL4(wc4[0], 608);  GL4(wc4[1], 624);
        GL1(bcv, 640);
        WAITV0();
        float bbf[8] = { bb4[0].x, bb4[0].y, bb4[0].z, bb4[0].w,
                         bb4[1].x, bb4[1].y, bb4[1].z, bb4[1].w };
        float wcf[8] = { wc4[0].x, wc4[0].y, wc4[0].z, wc4[0].w,
                         wc4[1].x, wc4[1].y, wc4[1].z, wc4[1].w };
        z = bcv;
        #pragma unroll
        for (int j = 0; j < 8; j++) {
            const float4 w0 = wb4[4 * j + 0], w1 = wb4[4 * j + 1];
            const float4 w2 = wb4[4 * j + 2], w3 = wb4[4 * j + 3];
            const float bj = bbf[j], wc = wcf[j];
            float s0 = bj, s1 = 0.f, s2 = 0.f, s3 = 0.f;
            s0 = fmaf(w0.x, h3[0],  s0); s1 = fmaf(w0.y, h3[1],  s1);
            s2 = fmaf(w0.z, h3[2],  s2); s3 = fmaf(w0.w, h3[3],  s3);
            s0 = fmaf(w1.x, h3[4],  s0); s1 = fmaf(w1.y, h3[5],  s1);
            s2 = fmaf(w1.z, h3[6],  s2); s3 = fmaf(w1.w, h3[7],  s3);
            s0 = fmaf(w2.x, h3[8],  s0); s1 = fmaf(w2.y, h3[9],  s1);
            s2 = fmaf(w2.z, h3[10], s2); s3 = fmaf(w2.w, h3[11], s3);
            s0 = fmaf(w3.x, h3[12], s0); s1 = fmaf(w3.y, h3[13], s1);
            s2 = fmaf(w3.z, h3[14], s2); s3 = fmaf(w3.w, h3[15], s3);
            z = fmaf(wc, fmaxf((s0 + s1) + (s2 + s3), 0.f), z);
        }
    }

    {
        const float sp = fmaxf(z, 0.f) + log1pf(expf(-fabsf(z)));
        scores[p] = sp;
        const unsigned bin = __float_as_uint(sp) >> 16;      // < 32768
        atomicAdd(&histL[bin >> 1], 1u << (16 * (bin & 1))); // packed u16
    }
    __syncthreads();

    // merge private hist: only nonzero 16-bit fields hit global atomics
    {
        const uint4* h4 = (const uint4*)histL;
        for (int i = t; i < NB1 / 8; i += 256) {
            const uint4 v = h4[i];
            const int b0 = 8 * i;
            const unsigned w[4] = { v.x, v.y, v.z, v.w };
            #pragma unroll
            for (int k = 0; k < 4; k++) {
                const unsigned lo = w[k] & 0xFFFFu;
                const unsigned hi = w[k] >> 16;
                if (lo) atomicAdd(&hist1[b0 + 2 * k + 0], lo);
                if (hi) atomicAdd(&hist1[b0 + 2 * k + 1], hi);
            }
        }
    }
}

// ---------------------------------------------------------------------------
// K2: refine. 64 blocks x 256 threads, fully parallel. Each block: redundant
// level-1 threshold (B* = max bin with suffix >= 64, tail1 = suffix(B*+1));
// then over its 1024-score slice: compact hi >= B* into global cand and
// histogram bin-B* members into 4096 sub-bins (bits 15:4). Block 0
// publishes {B*, tail1}.
// ---------------------------------------------------------------------------
__global__ __launch_bounds__(256) void refine_kernel(
    const unsigned* __restrict__ hist1, const float* __restrict__ scores,
    unsigned* __restrict__ hist2, int* __restrict__ meta,
    u64* __restrict__ cand)
{
    __shared__ unsigned csum[256];
    __shared__ unsigned bsum[128];
    __shared__ int sh_c, sh_B;
    __shared__ unsigned sh_tail;
    const int t = threadIdx.x;

    {
        unsigned s = 0;
        const uint4* h4 = (const uint4*)(hist1 + t * 128);
        #pragma unroll
        for (int i = 0; i < 32; i++) {
            const uint4 v = h4[i];
            s += v.x + v.y + v.z + v.w;
        }
        csum[t] = s;
    }
    __syncthreads();
    for (int d = 1; d < 256; d <<= 1) {
        const unsigned v = (t + d < 256) ? csum[t + d] : 0u;
        __syncthreads();
        csum[t] += v;
        __syncthreads();
    }
    {
        const unsigned here = csum[t];
        const unsigned nxt = (t + 1 < 256) ? csum[t + 1] : 0u;
        if (here >= 64u && nxt < 64u) sh_c = t;
    }
    __syncthreads();
    const int cstar = sh_c;
    if (t < 128) bsum[t] = hist1[cstar * 128 + t];
    __syncthreads();
    {
        const unsigned ctail = (cstar + 1 < 256) ? csum[cstar + 1] : 0u;
        for (int d = 1; d < 128; d <<= 1) {
            unsigned v = 0u;
            if (t < 128 && t + d < 128) v = bsum[t + d];
            __syncthreads();
            if (t < 128) bsum[t] += v;
            __syncthreads();
        }
        if (t < 128) {
            const unsigned here = bsum[t] + ctail;
            const unsigned nxt = (t + 1 < 128) ? bsum[t + 1] + ctail : ctail;
            if (here >= 64u && nxt < 64u) { sh_B = cstar * 128 + t; sh_tail = nxt; }
        }
    }
    __syncthreads();
    const unsigned Bstar = (unsigned)sh_B;
    if (blockIdx.x == 0 && t == 0) { meta[0] = sh_B; meta[1] = (int)sh_tail; }

    // slice pass: compact level-1 candidates + build sub-histogram
    const float4* s4 = (const float4*)scores;
    const int i = blockIdx.x * 256 + t;
    const float4 v = s4[i];
    const int n0 = 4 * i;
    #pragma unroll
    for (int k = 0; k < 4; k++) {
        const float sv = (k == 0) ? v.x : (k == 1) ? v.y : (k == 2) ? v.z : v.w;
        const unsigned b = __float_as_uint(sv);
        const unsigned hi = b >> 16;
        if (hi >= Bstar) {
            const int p = atomicAdd(&meta[2], 1);
            if (p < CAND_CAP) cand[p] = ((u64)b << 32) | (unsigned)~(n0 + k);
            if (hi == Bstar) atomicAdd(&hist2[(b & 0xFFFFu) >> 4], 1u);
        }
    }
}

// ---------------------------------------------------------------------------
// K3: final. 1 block x 256 threads. Level-2 threshold T2 (sub-bin, bits
// 15:4) -> filter cands to ~64+ties -> rank-select (exact lax.top_k tie
// order via key (bits<<32)|~idx) -> gather out[b,k,c] = src[b,c,idx[k]].
// ---------------------------------------------------------------------------
__global__ __launch_bounds__(256) void final_kernel(
    const unsigned* __restrict__ hist2, const int* __restrict__ meta,
    const u64* __restrict__ cand, const float* __restrict__ src,
    float* __restrict__ out)
{
    __shared__ unsigned h2[NB2];       // 16 KB
    __shared__ unsigned csum[256];
    __shared__ u64 keys[FCAP];
    __shared__ int idxs[64];
    __shared__ int sh_c, sh_T2, sh_cnt;
    const int t = threadIdx.x;
    const unsigned Bstar = (unsigned)meta[0];
    const unsigned tail1 = (unsigned)meta[1];

    // load hist2 to LDS
    {
        uint4* d = (uint4*)h2;
        const uint4* s = (const uint4*)hist2;
        #pragma unroll
        for (int i = 0; i < 4; i++) d[t + 256 * i] = s[t + 256 * i];
    }
    __syncthreads();

    // chunk sums: 16 bins/thread
    {
        unsigned s = 0;
        #pragma unroll
        for (int i = 0; i < 16; i++) s += h2[t * 16 + i];
        csum[t] = s;
    }
    __syncthreads();
    for (int d = 1; d < 256; d <<= 1) {
        const unsigned v = (t + d < 256) ? csum[t + d] : 0u;
        __syncthreads();
        csum[t] += v;
        __syncthreads();
    }
    {
        const unsigned here = tail1 + csum[t];
        const unsigned nxt = tail1 + ((t + 1 < 256) ? csum[t + 1] : 0u);
        if (here >= 64u && nxt < 64u) sh_c = t;
    }
    __syncthreads();
    {
        const int c2 = sh_c;
        if (t == 0) {
            unsigned acc = tail1 + ((c2 + 1 < 256) ? csum[c2 + 1] : 0u);
            int T2 = c2 * 16;
            for (int b = c2 * 16 + 15; b >= c2 * 16; b--) {
                acc += h2[b];
                if (acc >= 64u) { T2 = b; break; }
            }
            sh_T2 = T2;
            sh_cnt = 0;
        }
    }
    __syncthreads();
    const unsigned T2 = (unsigned)sh_T2;

    // filter candidates: hi > B*  OR  sub-bin >= T2
    int count = meta[2];
    if (count > CAND_CAP) count = CAND_CAP;
    for (int i = t; i < count; i += 256) {
        const u64 key = cand[i];
        const unsigned b = (unsigned)(key >> 32);
        const unsigned hi = b >> 16;
        if (hi > Bstar || ((b & 0xFFFFu) >> 4) >= T2) {
            const int p = atomicAdd(&sh_cnt, 1);
            if (p < FCAP) keys[p] = key;
        }
    }
    __syncthreads();

    // rank-select top-64 (keys unique -> ranks form a permutation)
    int fcnt = sh_cnt;
    if (fcnt > FCAP) fcnt = FCAP;
    for (int i = t; i < fcnt; i += 256) {
        const u64 me = keys[i];
        int r = 0;
        for (int j = 0; j < fcnt; j++) r += (keys[j] > me);
        if (r < 64) idxs[r] = (int)~(unsigned)(me & 0xFFFFFFFFu);
    }
    __syncthreads();

    // gather: out[b, k, c] = src[b, c, idx[k]]
    for (int e = t; e < 3072; e += 256) {
        const int b  = e / 384;
        const int rr = e % 384;
        const int kk = rr / 6;
        const int c  = rr % 6;
        out[e] = src[(b * 6 + c) * N_PTS + idxs[kk]];
    }
}

extern "C" void kernel_launch(void* const* d_in, const int* in_sizes, int n_in,
                              void* d_out, int out_size, void* d_ws, size_t ws_size,
                              hipStream_t stream)
{
    const float* src = (const float*)d_in[0];
    const float* W1 = (const float*)d_in[2];
    const float* b1 = (const float*)d_in[3];
    const float* W2 = (const float*)d_in[4];
    const float* b2 = (const float*)d_in[5];
    const float* Wa = (const float*)d_in[6];
    const float* ba = (const float*)d_in[7];
    const float* Wb = (const float*)d_in[8];
    const float* bb = (const float*)d_in[9];
    const float* Wc = (const float*)d_in[10];
    const float* bc = (const float*)d_in[11];

    char* ws = (char*)d_ws;
    float*    scores = (float*)ws;                          // 256 KB
    unsigned* hist1  = (unsigned*)(ws + 256 * 1024);        // 128 KB
    unsigned* hist2  = (unsigned*)(ws + 384 * 1024);        // 16 KB
    int*      meta   = (int*)(ws + 400 * 1024);             // 64 B
    u64*      cand   = (u64*)(ws + 408 * 1024);             // 32 KB
    float*    pk     = (float*)(ws + 440 * 1024);           // 16 KB blob
    float*    out    = (float*)d_out;

    // zero hist1+hist2+meta (contiguous): (32768+4096+16)/4 = 9220 uint4
    // + last block packs the uniform weight blob
    const int n4 = (NB1 + NB2 + 16) / 4;
    zero_pack_kernel<<<(n4 + 255) / 256 + 1, 256, 0, stream>>>(
        (uint4*)hist1, n4, W1, b1, W2, b2, Wa, ba, Wb, bb, Wc, bc, pk);
    score_kernel<<<256, 256, 0, stream>>>(src, pk, scores, hist1);
    refine_kernel<<<64, 256, 0, stream>>>(hist1, scores, hist2, meta, cand);
    final_kernel<<<1, 256, 0, stream>>>(hist2, meta, cand, src, out);
}

// Round 5
// 135.276 us; speedup vs baseline: 1.2740x; 1.2740x over previous
//
#include <hip/hip_runtime.h>
#include <stdint.h>

#define N_PTS 65536
#define NB1 32768        // level-1 bins: score bits 31:16
#define NB2 4096         // level-2 bins: score bits 15:4 within bin B*
#define CAND_CAP 4096
#define FCAP 1024
typedef unsigned long long u64;

// ws layout (zero region [256K, 256K+144K+64) contiguous)
//   [0    , 256K)        scores  f32[65536]
//   [256K , 384K)        hist1   u32[32768]
//   [384K , 400K)        hist2   u32[4096]
//   [400K , 400K+64)     meta    i32 {0:Bstar, 1:tail1, 2:cand_count}
//   [408K , 440K)        cand    u64[4096]   (not zeroed; meta[2] counts)

__global__ __launch_bounds__(256) void zero_kernel(uint4* __restrict__ z, int n4)
{
    const int i = blockIdx.x * 256 + threadIdx.x;
    const uint4 zz = {0u, 0u, 0u, 0u};
    if (i < n4) z[i] = zz;
}

// ---------------------------------------------------------------------------
// K1: MLP score (batch 0). 128 blocks x 256 threads (4 waves/CU, 1 block/CU
// due to 128K LDS hist), TWO points per thread (p0=base+t, p1=base+256+t).
// This is the R0-proven kernel (135.6us total) plus ONE surgical change:
// sched_group_barrier directives in the jb loop forcing the scheduler to
// emit [24 x ds_read_b128 cluster][VALU cluster] per iteration. R1-R4
// showed every fetch mechanism ends up load-serialized when the compiler
// schedules freely (VGPR=88 = batch never live); asm alternatives either
// get vmcnt-drained (R3) or corrupt under RA spill (R4). SGB keeps the
// dataflow in C++ (compiler emits correct COUNTED lgkmcnt waits; spills
// stay correct) while overriding the scheduler's dribble.
// LDS-private histogram (R8's proven fix for the global-atomic drain).
// ---------------------------------------------------------------------------
__global__ __launch_bounds__(256, 1) void score_kernel(
    const float* __restrict__ src,
    const float* __restrict__ W1, const float* __restrict__ b1,
    const float* __restrict__ W2, const float* __restrict__ b2,
    const float* __restrict__ Wa, const float* __restrict__ ba,
    const float* __restrict__ Wb, const float* __restrict__ bb,
    const float* __restrict__ Wc, const float* __restrict__ bc,
    float* __restrict__ scores, unsigned* __restrict__ hist1)
{
    __shared__ unsigned histL[NB1];                // 128 KB
    __shared__ __align__(16) float sW1[32 * 8];    // [j][0:6]=w, [6]=bias, [7]=0
    __shared__ __align__(16) float sW2[64 * 32];   // [j][i]
    __shared__ __align__(16) float sWaT[64 * 16];  // [j][q] (transposed Wa)
    __shared__ __align__(16) float sWb[8 * 16];    // [j][q]
    __shared__ float sb2[64], sba[16], sbb[8], sWc[8], sbc1[1];
    const int t = threadIdx.x;

    // zero LDS hist: 8192 uint4 / 256 thr = 32 per thread
    {
        uint4* h4 = (uint4*)histL;
        const uint4 zz = {0u, 0u, 0u, 0u};
        #pragma unroll
        for (int i = 0; i < 32; i++) h4[t + 256 * i] = zz;
    }
    // stage weights
    {
        const int j = t >> 3, c = t & 7;
        sW1[t] = (c < 6) ? W1[j * 6 + c] : ((c == 6) ? b1[j] : 0.f);
    }
    for (int i = t; i < 2048; i += 256) sW2[i] = W2[i];
    for (int i = t; i < 1024; i += 256) {
        const int j = i >> 4, q = i & 15;
        sWaT[i] = Wa[q * 64 + j];
    }
    if (t < 128) sWb[t] = Wb[t];
    if (t < 64)  sb2[t] = b2[t];
    if (t < 16)  sba[t] = ba[t];
    if (t < 8)   { sbb[t] = bb[t]; sWc[t] = Wc[t]; }
    if (t == 0)  sbc1[0] = bc[0];
    __syncthreads();

    const int base = blockIdx.x * 512;
    const int p[2] = { base + t, base + 256 + t };

    float x[2][6];
    #pragma unroll
    for (int c = 0; c < 6; c++) {
        x[0][c] = src[c * N_PTS + p[0]];
        x[1][c] = src[c * N_PTS + p[1]];
    }

    // ---- layer 1: 6 -> 32, both points ----
    float h1[2][32];
    #pragma unroll
    for (int j = 0; j < 32; j++) {
        const float4 wA = *(const float4*)&sW1[j * 8];
        const float4 wB = *(const float4*)&sW1[j * 8 + 4];   // .z = bias
        #pragma unroll
        for (int P = 0; P < 2; P++) {
            float a = wB.z;
            a = fmaf(wA.x, x[P][0], a); a = fmaf(wA.y, x[P][1], a);
            a = fmaf(wA.z, x[P][2], a); a = fmaf(wA.w, x[P][3], a);
            a = fmaf(wB.x, x[P][4], a); a = fmaf(wB.y, x[P][5], a);
            h1[P][j] = fmaxf(a, 0.f);
        }
    }

    // ---- layers 2+3 fused: 32 -> 64 -> 16, neuron pairs, both points ----
    float h3[2][16];
    #pragma unroll
    for (int q = 0; q < 16; q++) { h3[0][q] = sba[q]; h3[1][q] = sba[q]; }

    #pragma unroll 1
    for (int jb = 0; jb < 32; jb++) {
        const int j0 = 2 * jb, j1 = j0 + 1;
        const float4* r0 = (const float4*)&sW2[j0 * 32];
        const float4* r1 = (const float4*)&sW2[j1 * 32];
        const float4* wa0 = (const float4*)&sWaT[j0 * 16];
        const float4* wa1 = (const float4*)&sWaT[j1 * 16];
        // 24 independent b128 loads, issued as one batch
        float4 u[8], v[8], q0[4], q1[4];
        #pragma unroll
        for (int i = 0; i < 8; i++) u[i] = r0[i];
        #pragma unroll
        for (int i = 0; i < 8; i++) v[i] = r1[i];
        #pragma unroll
        for (int i = 0; i < 4; i++) q0[i] = wa0[i];
        #pragma unroll
        for (int i = 0; i < 4; i++) q1[i] = wa1[i];
        const float bj0 = sb2[j0], bj1 = sb2[j1];

        #pragma unroll
        for (int P = 0; P < 2; P++) {
            float a0 = 0.f, a1 = 0.f, a2 = 0.f, a3 = 0.f;  // neuron j0
            float c0 = 0.f, c1 = 0.f, c2 = 0.f, c3 = 0.f;  // neuron j1
            #pragma unroll
            for (int i4 = 0; i4 < 8; i4++) {
                const float h0 = h1[P][4 * i4 + 0], hh1 = h1[P][4 * i4 + 1];
                const float h2 = h1[P][4 * i4 + 2], hh3 = h1[P][4 * i4 + 3];
                a0 = fmaf(u[i4].x, h0, a0); a1 = fmaf(u[i4].y, hh1, a1);
                a2 = fmaf(u[i4].z, h2, a2); a3 = fmaf(u[i4].w, hh3, a3);
                c0 = fmaf(v[i4].x, h0, c0); c1 = fmaf(v[i4].y, hh1, c1);
                c2 = fmaf(v[i4].z, h2, c2); c3 = fmaf(v[i4].w, hh3, c3);
            }
            const float v0 = fmaxf((a0 + a1) + (a2 + a3) + bj0, 0.f);
            const float v1 = fmaxf((c0 + c1) + (c2 + c3) + bj1, 0.f);
            #pragma unroll
            for (int q4 = 0; q4 < 4; q4++) {
                float t0 = h3[P][4 * q4 + 0], t1 = h3[P][4 * q4 + 1];
                float t2 = h3[P][4 * q4 + 2], t3 = h3[P][4 * q4 + 3];
                t0 = fmaf(q0[q4].x, v0, t0); t1 = fmaf(q0[q4].y, v0, t1);
                t2 = fmaf(q0[q4].z, v0, t2); t3 = fmaf(q0[q4].w, v0, t3);
                t0 = fmaf(q1[q4].x, v1, t0); t1 = fmaf(q1[q4].y, v1, t1);
                t2 = fmaf(q1[q4].z, v1, t2); t3 = fmaf(q1[q4].w, v1, t3);
                h3[P][4 * q4 + 0] = t0; h3[P][4 * q4 + 1] = t1;
                h3[P][4 * q4 + 2] = t2; h3[P][4 * q4 + 3] = t3;
            }
        }

        // Force the scheduler: cluster ALL the iteration's LDS reads first
        // (26 = 24 b128 + bias reads), then the FMA block. Dataflow stays
        // C++-visible, so waitcnt insertion emits counted lgkmcnt before
        // the first consumer and everything downstream remains correct.
        // Masks (LLVM SchedGroupMask): DS_READ=0x100, VALU=0x2.
        __builtin_amdgcn_sched_group_barrier(0x100, 26, 0);
        __builtin_amdgcn_sched_group_barrier(0x002, 256, 0);
    }
    #pragma unroll
    for (int q = 0; q < 16; q++) {
        h3[0][q] = fmaxf(h3[0][q], 0.f);
        h3[1][q] = fmaxf(h3[1][q], 0.f);
    }

    // ---- layers 4+5: 16 -> 8 -> 1, both points ----
    float z[2] = { sbc1[0], sbc1[0] };
    #pragma unroll
    for (int j = 0; j < 8; j++) {
        const float4* wbr = (const float4*)&sWb[j * 16];
        const float4 w0 = wbr[0], w1 = wbr[1], w2 = wbr[2], w3 = wbr[3];
        const float bj = sbb[j], wc = sWc[j];
        #pragma unroll
        for (int P = 0; P < 2; P++) {
            float s0 = bj, s1 = 0.f, s2 = 0.f, s3 = 0.f;
            s0 = fmaf(w0.x, h3[P][0],  s0); s1 = fmaf(w0.y, h3[P][1],  s1);
            s2 = fmaf(w0.z, h3[P][2],  s2); s3 = fmaf(w0.w, h3[P][3],  s3);
            s0 = fmaf(w1.x, h3[P][4],  s0); s1 = fmaf(w1.y, h3[P][5],  s1);
            s2 = fmaf(w1.z, h3[P][6],  s2); s3 = fmaf(w1.w, h3[P][7],  s3);
            s0 = fmaf(w2.x, h3[P][8],  s0); s1 = fmaf(w2.y, h3[P][9],  s1);
            s2 = fmaf(w2.z, h3[P][10], s2); s3 = fmaf(w2.w, h3[P][11], s3);
            s0 = fmaf(w3.x, h3[P][12], s0); s1 = fmaf(w3.y, h3[P][13], s1);
            s2 = fmaf(w3.z, h3[P][14], s2); s3 = fmaf(w3.w, h3[P][15], s3);
            z[P] = fmaf(wc, fmaxf((s0 + s1) + (s2 + s3), 0.f), z[P]);
        }
    }

    #pragma unroll
    for (int P = 0; P < 2; P++) {
        const float sp = fmaxf(z[P], 0.f) + log1pf(expf(-fabsf(z[P])));
        scores[p[P]] = sp;
        atomicAdd(&histL[__float_as_uint(sp) >> 16], 1u);   // LDS atomic
    }
    __syncthreads();

    // merge private hist: only nonzero bins hit global atomics
    for (int i = t; i < NB1; i += 256) {
        const unsigned v = histL[i];
        if (v) atomicAdd(&hist1[i], v);
    }
}

// ---------------------------------------------------------------------------
// K2: refine. 64 blocks x 256 threads, fully parallel (no last-block serial
// scan — R9's 65us mistake). Each block: redundant level-1 threshold
// (B* = max bin with suffix >= 64, tail1 = suffix(B*+1)); then over its
// 1024-score slice: compact hi >= B* into global cand (count <= 4096,
// validated R2-R7) and histogram bin-B* members into 4096 sub-bins
// (bits 15:4). Block 0 publishes {B*, tail1}.
// ---------------------------------------------------------------------------
__global__ __launch_bounds__(256) void refine_kernel(
    const unsigned* __restrict__ hist1, const float* __restrict__ scores,
    unsigned* __restrict__ hist2, int* __restrict__ meta,
    u64* __restrict__ cand)
{
    __shared__ unsigned csum[256];
    __shared__ unsigned bsum[128];
    __shared__ int sh_c, sh_B;
    __shared__ unsigned sh_tail;
    const int t = threadIdx.x;

    {
        unsigned s = 0;
        const uint4* h4 = (const uint4*)(hist1 + t * 128);
        #pragma unroll
        for (int i = 0; i < 32; i++) {
            const uint4 v = h4[i];
            s += v.x + v.y + v.z + v.w;
        }
        csum[t] = s;
    }
    __syncthreads();
    for (int d = 1; d < 256; d <<= 1) {
        const unsigned v = (t + d < 256) ? csum[t + d] : 0u;
        __syncthreads();
        csum[t] += v;
        __syncthreads();
    }
    {
        const unsigned here = csum[t];
        const unsigned nxt = (t + 1 < 256) ? csum[t + 1] : 0u;
        if (here >= 64u && nxt < 64u) sh_c = t;
    }
    __syncthreads();
    const int cstar = sh_c;
    if (t < 128) bsum[t] = hist1[cstar * 128 + t];
    __syncthreads();
    {
        const unsigned ctail = (cstar + 1 < 256) ? csum[cstar + 1] : 0u;
        for (int d = 1; d < 128; d <<= 1) {
            unsigned v = 0u;
            if (t < 128 && t + d < 128) v = bsum[t + d];
            __syncthreads();
            if (t < 128) bsum[t] += v;
            __syncthreads();
        }
        if (t < 128) {
            const unsigned here = bsum[t] + ctail;
            const unsigned nxt = (t + 1 < 128) ? bsum[t + 1] + ctail : ctail;
            if (here >= 64u && nxt < 64u) { sh_B = cstar * 128 + t; sh_tail = nxt; }
        }
    }
    __syncthreads();
    const unsigned Bstar = (unsigned)sh_B;
    if (blockIdx.x == 0 && t == 0) { meta[0] = sh_B; meta[1] = (int)sh_tail; }

    // slice pass: compact level-1 candidates + build sub-histogram
    const float4* s4 = (const float4*)scores;
    const int i = blockIdx.x * 256 + t;
    const float4 v = s4[i];
    const int n0 = 4 * i;
    #pragma unroll
    for (int k = 0; k < 4; k++) {
        const float sv = (k == 0) ? v.x : (k == 1) ? v.y : (k == 2) ? v.z : v.w;
        const unsigned b = __float_as_uint(sv);
        const unsigned hi = b >> 16;
        if (hi >= Bstar) {
            const int p = atomicAdd(&meta[2], 1);
            if (p < CAND_CAP) cand[p] = ((u64)b << 32) | (unsigned)~(n0 + k);
            if (hi == Bstar) atomicAdd(&hist2[(b & 0xFFFFu) >> 4], 1u);
        }
    }
}

// ---------------------------------------------------------------------------
// K3: final. 1 block x 256 threads, touches only small data (16KB hist2 +
// 32KB cand). Level-2 threshold T2 (sub-bin, bits 15:4) -> filter cands to
// ~64+ties -> rank-select (exact lax.top_k tie order via key
// (bits<<32)|~idx) -> gather out[b,k,c] = src[b,c,idx[k]].
// ---------------------------------------------------------------------------
__global__ __launch_bounds__(256) void final_kernel(
    const unsigned* __restrict__ hist2, const int* __restrict__ meta,
    const u64* __restrict__ cand, const float* __restrict__ src,
    float* __restrict__ out)
{
    __shared__ unsigned h2[NB2];       // 16 KB
    __shared__ unsigned csum[256];
    __shared__ u64 keys[FCAP];
    __shared__ int idxs[64];
    __shared__ int sh_c, sh_T2, sh_cnt;
    const int t = threadIdx.x;
    const unsigned Bstar = (unsigned)meta[0];
    const unsigned tail1 = (unsigned)meta[1];

    // load hist2 to LDS
    {
        uint4* d = (uint4*)h2;
        const uint4* s = (const uint4*)hist2;
        #pragma unroll
        for (int i = 0; i < 4; i++) d[t + 256 * i] = s[t + 256 * i];
    }
    __syncthreads();

    // chunk sums: 16 bins/thread
    {
        unsigned s = 0;
        #pragma unroll
        for (int i = 0; i < 16; i++) s += h2[t * 16 + i];
        csum[t] = s;
    }
    __syncthreads();
    for (int d = 1; d < 256; d <<= 1) {
        const unsigned v = (t + d < 256) ? csum[t + d] : 0u;
        __syncthreads();
        csum[t] += v;
        __syncthreads();
    }
    {
        const unsigned here = tail1 + csum[t];
        const unsigned nxt = tail1 + ((t + 1 < 256) ? csum[t + 1] : 0u);
        if (here >= 64u && nxt < 64u) sh_c = t;
    }
    __syncthreads();
    {
        const int c2 = sh_c;
        if (t == 0) {
            unsigned acc = tail1 + ((c2 + 1 < 256) ? csum[c2 + 1] : 0u);
            int T2 = c2 * 16;
            for (int b = c2 * 16 + 15; b >= c2 * 16; b--) {
                acc += h2[b];
                if (acc >= 64u) { T2 = b; break; }
            }
            sh_T2 = T2;
            sh_cnt = 0;
        }
    }
    __syncthreads();
    const unsigned T2 = (unsigned)sh_T2;

    // filter candidates: hi > B*  OR  sub-bin >= T2
    int count = meta[2];
    if (count > CAND_CAP) count = CAND_CAP;
    for (int i = t; i < count; i += 256) {
        const u64 key = cand[i];
        const unsigned b = (unsigned)(key >> 32);
        const unsigned hi = b >> 16;
        if (hi > Bstar || ((b & 0xFFFFu) >> 4) >= T2) {
            const int p = atomicAdd(&sh_cnt, 1);
            if (p < FCAP) keys[p] = key;
        }
    }
    __syncthreads();

    // rank-select top-64 (keys unique -> ranks form a permutation)
    int fcnt = sh_cnt;
    if (fcnt > FCAP) fcnt = FCAP;
    for (int i = t; i < fcnt; i += 256) {
        const u64 me = keys[i];
        int r = 0;
        for (int j = 0; j < fcnt; j++) r += (keys[j] > me);
        if (r < 64) idxs[r] = (int)~(unsigned)(me & 0xFFFFFFFFu);
    }
    __syncthreads();

    // gather: out[b, k, c] = src[b, c, idx[k]]
    for (int e = t; e < 3072; e += 256) {
        const int b  = e / 384;
        const int rr = e % 384;
        const int kk = rr / 6;
        const int c  = rr % 6;
        out[e] = src[(b * 6 + c) * N_PTS + idxs[kk]];
    }
}

extern "C" void kernel_launch(void* const* d_in, const int* in_sizes, int n_in,
                              void* d_out, int out_size, void* d_ws, size_t ws_size,
                              hipStream_t stream)
{
    const float* src = (const float*)d_in[0];
    const float* W1 = (const float*)d_in[2];
    const float* b1 = (const float*)d_in[3];
    const float* W2 = (const float*)d_in[4];
    const float* b2 = (const float*)d_in[5];
    const float* Wa = (const float*)d_in[6];
    const float* ba = (const float*)d_in[7];
    const float* Wb = (const float*)d_in[8];
    const float* bb = (const float*)d_in[9];
    const float* Wc = (const float*)d_in[10];
    const float* bc = (const float*)d_in[11];

    char* ws = (char*)d_ws;
    float*    scores = (float*)ws;                          // 256 KB
    unsigned* hist1  = (unsigned*)(ws + 256 * 1024);        // 128 KB
    unsigned* hist2  = (unsigned*)(ws + 384 * 1024);        // 16 KB
    int*      meta   = (int*)(ws + 400 * 1024);             // 64 B
    u64*      cand   = (u64*)(ws + 408 * 1024);             // 32 KB
    float*    out    = (float*)d_out;

    // zero hist1+hist2+meta (contiguous): (32768+4096+16)/4 = 9220 uint4
    const int n4 = (NB1 + NB2 + 16) / 4;
    zero_kernel<<<(n4 + 255) / 256, 256, 0, stream>>>((uint4*)hist1, n4);
    score_kernel<<<128, 256, 0, stream>>>(src, W1, b1, W2, b2, Wa, ba,
                                          Wb, bb, Wc, bc, scores, hist1);
    refine_kernel<<<64, 256, 0, stream>>>(hist1, scores, hist2, meta, cand);
    final_kernel<<<1, 256, 0, stream>>>(hist2, meta, cand, src, out);
}